// Round 2
// baseline (333.775 us; speedup 1.0000x reference)
//
#include <hip/hip_runtime.h>

#define N_NODES 100000
#define N_EDGES 1600000
#define D 128
#define RPB 64                        // node rows per bucket
#define NBUCKET 1563                  // ceil(N_NODES / RPB)
#define NBLK 196                      // edge chunks
#define EPB 8192                      // edges per chunk
#define AGG_CAP 1280                  // max edges per bucket (mean 1024, +8 sigma)
#define XCB 3125                      // xconv blocks (3.2M float4 / 1024)
#define SCAN_PAD 1792                 // 256*7 >= NBUCKET
#define NSLICE 8                      // XCD column slices (16 cols = 32 B each)

constexpr float LN_EPS   = 1e-5f;
constexpr float MEAN_EPS = 1e-8f;

typedef __attribute__((ext_vector_type(8))) short bf16x8;
typedef __attribute__((ext_vector_type(4))) float f32x4;

__device__ inline float bflo(unsigned p) {
  union { unsigned u; float f; } v; v.u = p << 16; return v.f;
}
__device__ inline float bfhi(unsigned p) {
  union { unsigned u; float f; } v; v.u = p & 0xFFFF0000u; return v.f;
}
__device__ inline unsigned short f2bf(float f) {
  union { float f; unsigned u; } v; v.f = f;
  return (unsigned short)((v.u + 0x7FFFu + ((v.u >> 16) & 1u)) >> 16);
}

// ---------------------------------------------------------------------------
// Fused prep: blocks [0,NBLK) = per-chunk bucket sort (hist -> local scan ->
// LDS scatter -> dense coalesced write + packed/transposed chunkoff).
// [NBLK,NBLK+XCB) = x->bf16. Last 16 = W concat + bias.
// ---------------------------------------------------------------------------
__global__ __launch_bounds__(256) void prep_sort(
    const float* __restrict__ x, const int* __restrict__ ei,
    const float* __restrict__ Wself, const float* __restrict__ Wagg,
    const float* __restrict__ bself, const float* __restrict__ bagg,
    unsigned short* __restrict__ xb, unsigned short* __restrict__ wcat,
    float* __restrict__ bsum, unsigned* __restrict__ ent_sorted,
    int* __restrict__ chunkoff) {
  __shared__ int ent_s[EPB];        // 32 KB
  __shared__ int cnt_s[SCAN_PAD];   // 7 KB
  __shared__ int off_s[SCAN_PAD];   // 7 KB (becomes cursors after chunkoff write)
  __shared__ int sb[256];
  const int bid = blockIdx.x;
  const int t = threadIdx.x;

  if (bid < NBLK) {
    const int ebase = bid * EPB;
    const int nch = min(EPB, N_EDGES - ebase);       // last chunk: 2560
    const int base4 = bid * (EPB / 4);
    const int end4 = base4 + (nch >> 2);             // nch divisible by 4

    for (int i = t; i < SCAN_PAD; i += 256) cnt_s[i] = 0;
    __syncthreads();

    // pass 1: histogram
#pragma unroll
    for (int k = 0; k < EPB / 1024; ++k) {
      int i4 = base4 + k * 256 + t;
      if (i4 < end4) {
        int4 r = ((const int4*)ei)[i4];
        atomicAdd(&cnt_s[r.x >> 6], 1);
        atomicAdd(&cnt_s[r.y >> 6], 1);
        atomicAdd(&cnt_s[r.z >> 6], 1);
        atomicAdd(&cnt_s[r.w >> 6], 1);
      }
    }
    __syncthreads();

    // blocked exclusive scan over SCAN_PAD (=256*7) entries
    int psum = 0;
#pragma unroll
    for (int i = 0; i < 7; ++i) psum += cnt_s[t * 7 + i];
    sb[t] = psum;
    __syncthreads();
    for (int off = 1; off < 256; off <<= 1) {
      int u = (t >= off) ? sb[t - off] : 0;
      __syncthreads();
      sb[t] += u;
      __syncthreads();
    }
    int run = sb[t] - psum;
#pragma unroll
    for (int i = 0; i < 7; ++i) {
      off_s[t * 7 + i] = run;
      run += cnt_s[t * 7 + i];
    }
    __syncthreads();

    // packed transposed chunkoff: chunkoff[b*NBLK + chunk] = beg | (len<<14)
    for (int b = t; b < NBUCKET; b += 256)
      chunkoff[b * NBLK + bid] = off_s[b] | (cnt_s[b] << 14);
    __syncthreads();

    // pass 2: LDS scatter into bucket-sorted order (off_s as cursors)
#pragma unroll
    for (int k = 0; k < EPB / 1024; ++k) {
      int i4 = base4 + k * 256 + t;
      if (i4 < end4) {
        int4 r = ((const int4*)ei)[i4];
        int4 c = ((const int4*)(ei + N_EDGES))[i4];
        int p0 = atomicAdd(&off_s[r.x >> 6], 1);
        ent_s[p0] = ((r.x & 63) << 17) | c.x;
        int p1 = atomicAdd(&off_s[r.y >> 6], 1);
        ent_s[p1] = ((r.y & 63) << 17) | c.y;
        int p2 = atomicAdd(&off_s[r.z >> 6], 1);
        ent_s[p2] = ((r.z & 63) << 17) | c.z;
        int p3 = atomicAdd(&off_s[r.w >> 6], 1);
        ent_s[p3] = ((r.w & 63) << 17) | c.w;
      }
    }
    __syncthreads();

    // dense coalesced write-out
    for (int i = t; i < nch; i += 256)
      ent_sorted[ebase + i] = (unsigned)ent_s[i];
  } else if (bid < NBLK + XCB) {
    // ---- xconv: 4 float4 per thread -> bf16x4
    const int base = (bid - NBLK) * 1024;
#pragma unroll
    for (int k = 0; k < 4; ++k) {
      int i4 = base + k * 256 + t;   // XCB*1024 == 3.2M exact
      float4 v = ((const float4*)x)[i4];
      ushort4 o;
      o.x = f2bf(v.x); o.y = f2bf(v.y); o.z = f2bf(v.z); o.w = f2bf(v.w);
      ((ushort4*)xb)[i4] = o;
    }
  } else {
    // ---- wconv: 16 blocks cover 128x256 weights
    const int blk = bid - NBLK - XCB;
#pragma unroll
    for (int k = 0; k < 8; ++k) {
      int idx = blk * 2048 + k * 256 + t;
      int o = idx >> 8, kc = idx & 255;
      float v = (kc < 128) ? Wself[o * 128 + kc] : Wagg[o * 128 + (kc - 128)];
      wcat[o * 256 + kc] = f2bf(v);
    }
    if (blk == 0 && t < 128) bsum[t] = bself[t] + bagg[t];
  }
}

// ---------------------------------------------------------------------------
// row_sort: one block per bucket. Collect the bucket's entries from the 196
// chunk slices, counting-sort by row, and write the globally row-sorted col
// list + packed (beg|deg<<16) per node. Runs ONCE (the 8 slice blocks then
// skip all sorting). NT stores: these streams are consumed once.
// ---------------------------------------------------------------------------
__global__ __launch_bounds__(256) void row_sort(
    const unsigned* __restrict__ ent_sorted, const int* __restrict__ chunkoff,
    unsigned* __restrict__ col_sorted, unsigned* __restrict__ rowinfo) {
  __shared__ int ent_s[AGG_CAP];   // 5 KB
  __shared__ int col_s[AGG_CAP];   // 5 KB
  __shared__ int sb[256];
  __shared__ int cnt_s[RPB];
  __shared__ int off_s[RPB];
  __shared__ int cur_s[RPB];

  const int b = blockIdx.x;
  const int t = threadIdx.x;

  int beg = 0, len = 0;
  if (t < NBLK) {
    int pk = chunkoff[b * NBLK + t];
    beg = pk & 16383;
    len = pk >> 14;
  }
  sb[t] = len;
  __syncthreads();
  for (int off = 1; off < 256; off <<= 1) {
    int u = (t >= off) ? sb[t - off] : 0;
    __syncthreads();
    sb[t] += u;
    __syncthreads();
  }
  int n = sb[255]; if (n > AGG_CAP) n = AGG_CAP;
  int dst = sb[t] - len;
  if (t < NBLK) {
    const unsigned* src = ent_sorted + t * EPB + beg;
    for (int i = 0; i < len; ++i)
      if (dst + i < AGG_CAP) ent_s[dst + i] = (int)src[i];
  }
  __syncthreads();

  // row counting sort
  if (t < RPB) cnt_s[t] = 0;
  __syncthreads();
  for (int i = t; i < n; i += 256) atomicAdd(&cnt_s[ent_s[i] >> 17], 1);
  __syncthreads();
  if (t < RPB) off_s[t] = cnt_s[t];
  __syncthreads();
  for (int off = 1; off < RPB; off <<= 1) {
    int u = 0;
    if (t < RPB && t >= off) u = off_s[t - off];
    __syncthreads();
    if (t < RPB) off_s[t] += u;
    __syncthreads();
  }
  int excl = 0;
  if (t < RPB) excl = off_s[t] - cnt_s[t];
  __syncthreads();
  if (t < RPB) { off_s[t] = excl; cur_s[t] = excl; }
  __syncthreads();
  for (int i = t; i < n; i += 256) {
    int e = ent_s[i];
    int pos = atomicAdd(&cur_s[e >> 17], 1);
    col_s[pos] = e & 0x1FFFF;
  }
  __syncthreads();

  for (int i = t; i < n; i += 256)
    __builtin_nontemporal_store((unsigned)col_s[i],
                                col_sorted + (size_t)b * AGG_CAP + i);
  if (t < RPB)
    __builtin_nontemporal_store((unsigned)off_s[t] | ((unsigned)cnt_s[t] << 16),
                                rowinfo + b * RPB + t);
}

// ---------------------------------------------------------------------------
// agg_slice: grid = NBUCKET*8. Block (b = bid>>3, g = bid&7). With default
// round-robin dispatch, bid&7 == XCD id, so slice g's 3.2 MB column-slice of
// xb stays resident in XCD g's 4 MB L2 -> gather becomes L2 hits instead of
// the ~3 TB/s miss path. Col lists are streamed with nontemporal loads so
// they don't evict the hot slice. 32 groups of 8 lanes; group handles 2 rows;
// lane owns 2 columns of the 16-col slice. Mean stored bf16 (nontemporal)
// into the node's out-row bytes [g*32, g*32+32) — same format gemm expects.
// ---------------------------------------------------------------------------
__global__ __launch_bounds__(256) void agg_slice(
    const unsigned short* __restrict__ xb, const unsigned* __restrict__ col_sorted,
    const unsigned* __restrict__ rowinfo, float* __restrict__ out) {
  __shared__ unsigned cols_s[AGG_CAP];  // 5 KB
  __shared__ unsigned ri_s[RPB];

  const int bid = blockIdx.x;
  const int g = bid & 7;                // XCD slice
  const int b = bid >> 3;               // bucket
  const int t = threadIdx.x;

  if (t < RPB) ri_s[t] = __builtin_nontemporal_load(rowinfo + b * RPB + t);
  __syncthreads();
  const int n = (int)(ri_s[RPB - 1] & 0xFFFFu) + (int)(ri_s[RPB - 1] >> 16);
  for (int i = t; i < n; i += 256)
    cols_s[i] = __builtin_nontemporal_load(col_sorted + (size_t)b * AGG_CAP + i);
  __syncthreads();

  const int grp = t >> 3, gl = t & 7;   // 32 groups x 8 lanes
  const unsigned short* xg = xb + g * 16 + gl * 2;   // + col*128 (ushorts)

  for (int rr = grp; rr < RPB; rr += 32) {
    const unsigned ri = ri_s[rr];
    const int rbeg = (int)(ri & 0xFFFFu);
    const int deg = (int)(ri >> 16);
    float a0 = 0.f, a1 = 0.f;
    int j = 0;
    for (; j + 8 <= deg; j += 8) {
      unsigned p[8];
#pragma unroll
      for (int u = 0; u < 8; ++u) {
        unsigned col = cols_s[rbeg + j + u];
        p[u] = *(const unsigned*)(xg + (size_t)col * 128);
      }
#pragma unroll
      for (int u = 0; u < 8; ++u) { a0 += bflo(p[u]); a1 += bfhi(p[u]); }
    }
    if (j + 4 <= deg) {
      unsigned p[4];
#pragma unroll
      for (int u = 0; u < 4; ++u) {
        unsigned col = cols_s[rbeg + j + u];
        p[u] = *(const unsigned*)(xg + (size_t)col * 128);
      }
#pragma unroll
      for (int u = 0; u < 4; ++u) { a0 += bflo(p[u]); a1 += bfhi(p[u]); }
      j += 4;
    }
    for (; j < deg; ++j) {
      unsigned col = cols_s[rbeg + j];
      unsigned p = *(const unsigned*)(xg + (size_t)col * 128);
      a0 += bflo(p); a1 += bfhi(p);
    }
    const int node = (b << 6) + rr;
    if (node < N_NODES) {
      float inv = 1.0f / ((float)deg + MEAN_EPS);
      unsigned o = (unsigned)f2bf(a0 * inv) | ((unsigned)f2bf(a1 * inv) << 16);
      __builtin_nontemporal_store(o, (unsigned*)(out + (size_t)node * D) + g * 8 + gl);
    }
  }
}

// ---------------------------------------------------------------------------
// MFMA GEMM: C[100000x128] = [x_bf16 | mean_bf16] (K=256) @ Wcat^T + ReLU + LN
// B-only LDS (67.6 KB -> 2 blocks/CU), A streamed global->frags, per-wave
// in-register LN epilogue. (unchanged from R1)
// ---------------------------------------------------------------------------
__global__ __launch_bounds__(512, 4) void gemm_mfma_ln(
    const unsigned short* __restrict__ xb, const float* out_mean,
    const unsigned short* __restrict__ wcat, const float* __restrict__ bsum,
    const float* __restrict__ gamma, const float* __restrict__ beta,
    float* out) {
  __shared__ unsigned short Bs[128 * 264];   // 67.6 KB
  __shared__ float bias_s[128];

  const int t = threadIdx.x;
  const int w = t >> 6, lane = t & 63;
  const int q = lane >> 4, s = lane & 15;
  const int base = blockIdx.x * 128;

  if (t < 128) bias_s[t] = bsum[t];

#pragma unroll
  for (int r = 0; r < 8; ++r) {
    int f = r * 512 + t;
    int row = f >> 5, c = f & 31;
    uint4 v = *(const uint4*)(wcat + row * 256 + c * 8);
    *(uint4*)(Bs + row * 264 + c * 8) = v;
  }

  const int arow = base + w * 16 + s;
  const int asafe = (arow < N_NODES) ? arow : 0;
  const unsigned short* xrow = xb + (size_t)asafe * 128;
  const unsigned short* mrow = (const unsigned short*)(out_mean + (size_t)asafe * 128);
  bf16x8 a[8];
#pragma unroll
  for (int kk = 0; kk < 4; ++kk)
    a[kk] = *(const bf16x8*)(xrow + kk * 32 + q * 8);
#pragma unroll
  for (int kk = 0; kk < 4; ++kk)
    a[4 + kk] = *(const bf16x8*)(mrow + kk * 32 + q * 8);

  __syncthreads();

  f32x4 acc[8];
#pragma unroll
  for (int j = 0; j < 8; ++j) acc[j] = (f32x4)(0.0f);

#pragma unroll
  for (int kk = 0; kk < 8; ++kk) {
    const int ko = kk * 32 + q * 8;
#pragma unroll
    for (int j = 0; j < 8; ++j) {
      bf16x8 bv = *(const bf16x8*)(Bs + (j * 16 + s) * 264 + ko);
      acc[j] = __builtin_amdgcn_mfma_f32_16x16x32_bf16(a[kk], bv, acc[j], 0, 0, 0);
    }
  }

#pragma unroll
  for (int j = 0; j < 8; ++j) {
    float bb = bias_s[j * 16 + s];
#pragma unroll
    for (int r = 0; r < 4; ++r)
      acc[j][r] = fmaxf(acc[j][r] + bb, 0.0f);
  }

  float g[8], be[8];
#pragma unroll
  for (int j = 0; j < 8; ++j) {
    g[j]  = gamma[j * 16 + s];
    be[j] = beta[j * 16 + s];
  }

#pragma unroll
  for (int r = 0; r < 4; ++r) {
    float s1 = 0.f, s2 = 0.f;
#pragma unroll
    for (int j = 0; j < 8; ++j) {
      float h = acc[j][r];
      s1 += h; s2 += h * h;
    }
#pragma unroll
    for (int m = 1; m < 16; m <<= 1) {
      s1 += __shfl_xor(s1, m, 64);
      s2 += __shfl_xor(s2, m, 64);
    }
    int node = base + w * 16 + q * 4 + r;
    if (node < N_NODES) {
      float mu = s1 * (1.0f / 128.0f);
      float var = s2 * (1.0f / 128.0f) - mu * mu;
      float rstd = rsqrtf(var + LN_EPS);
      float* orow = out + (size_t)node * 128;
#pragma unroll
      for (int j = 0; j < 8; ++j)
        orow[j * 16 + s] = (acc[j][r] - mu) * rstd * g[j] + be[j];
    }
  }
}

extern "C" void kernel_launch(void* const* d_in, const int* in_sizes, int n_in,
                              void* d_out, int out_size, void* d_ws, size_t ws_size,
                              hipStream_t stream) {
  const float* x     = (const float*)d_in[0];
  const int*   ei    = (const int*)d_in[1];
  const float* Wagg  = (const float*)d_in[2];
  const float* bagg  = (const float*)d_in[3];
  const float* Wself = (const float*)d_in[4];
  const float* bself = (const float*)d_in[5];
  const float* gamma = (const float*)d_in[6];
  const float* beta  = (const float*)d_in[7];
  float* out = (float*)d_out;

  // ws: xb | wcat | bsum | ent_sorted | chunkoff | col_sorted | rowinfo (~41.7 MB)
  unsigned short* xb   = (unsigned short*)d_ws;                 // 25.6 MB
  unsigned short* wcat = xb + (size_t)N_NODES * D;              // 64 KB
  float* bsum      = (float*)(wcat + 128 * 256);                // 512 B
  unsigned* ent_sorted = (unsigned*)(bsum + 128);               // NBLK*EPB u32 (6.4 MB)
  int* chunkoff    = (int*)(ent_sorted + (size_t)NBLK * EPB);   // NBUCKET*NBLK (1.2 MB)
  unsigned* col_sorted = (unsigned*)(chunkoff + (size_t)NBUCKET * NBLK); // 8.0 MB
  unsigned* rowinfo    = col_sorted + (size_t)NBUCKET * AGG_CAP;         // 0.4 MB

  prep_sort<<<NBLK + XCB + 16, 256, 0, stream>>>(
      x, ei, Wself, Wagg, bself, bagg, xb, wcat, bsum, ent_sorted, chunkoff);

  row_sort<<<NBUCKET, 256, 0, stream>>>(ent_sorted, chunkoff, col_sorted, rowinfo);

  agg_slice<<<NBUCKET * NSLICE, 256, 0, stream>>>(xb, col_sorted, rowinfo, out);

  gemm_mfma_ln<<<(N_NODES + 127) / 128, 512, 0, stream>>>(
      xb, out, wcat, bsum, gamma, beta, out);
}

// Round 3
// 261.997 us; speedup vs baseline: 1.2740x; 1.2740x over previous
//
#include <hip/hip_runtime.h>

#define N_NODES 100000
#define N_EDGES 1600000
#define D 128
#define RPB 64                        // node rows per bucket
#define NBUCKET 1563                  // ceil(N_NODES / RPB)
#define NBLK 196                      // edge chunks
#define EPB 8192                      // edges per chunk
#define AGG_CAP 1280                  // max edges per bucket (mean 1024, +8 sigma)
#define XCB 3125                      // xconv blocks (12.8M floats / 4096)
#define SCAN_PAD 1792                 // 256*7 >= NBUCKET
#define NSLICE 8                      // XCD column slices (16 cols = 32 B each)
#define SLICE_STRIDE ((size_t)N_NODES * 16)   // ushorts per slice region

constexpr float LN_EPS   = 1e-5f;
constexpr float MEAN_EPS = 1e-8f;

typedef __attribute__((ext_vector_type(8))) short bf16x8;
typedef __attribute__((ext_vector_type(4))) float f32x4;

__device__ inline float bflo(unsigned p) {
  union { unsigned u; float f; } v; v.u = p << 16; return v.f;
}
__device__ inline float bfhi(unsigned p) {
  union { unsigned u; float f; } v; v.u = p & 0xFFFF0000u; return v.f;
}
__device__ inline unsigned short f2bf(float f) {
  union { float f; unsigned u; } v; v.f = f;
  return (unsigned short)((v.u + 0x7FFFu + ((v.u >> 16) & 1u)) >> 16);
}
__device__ inline unsigned pack2(float a, float b) {
  return (unsigned)f2bf(a) | ((unsigned)f2bf(b) << 16);
}

// ---------------------------------------------------------------------------
// Fused prep: blocks [0,NBLK) = per-chunk bucket sort (hist -> local scan ->
// LDS scatter -> dense coalesced write + packed/transposed chunkoff).
// [NBLK,NBLK+XCB) = x->bf16 writing BOTH row-major xb (for gemm A-frags) and
// slice-major xs (xs[slice][node][16], 32 B/slice-row -> per-XCD-L2-resident
// gather target). Last 16 blocks = W concat + bias.
// ---------------------------------------------------------------------------
__global__ __launch_bounds__(256) void prep_sort(
    const float* __restrict__ x, const int* __restrict__ ei,
    const float* __restrict__ Wself, const float* __restrict__ Wagg,
    const float* __restrict__ bself, const float* __restrict__ bagg,
    unsigned short* __restrict__ xb, unsigned short* __restrict__ xs,
    unsigned short* __restrict__ wcat, float* __restrict__ bsum,
    unsigned* __restrict__ ent_sorted, int* __restrict__ chunkoff) {
  __shared__ int ent_s[EPB];        // 32 KB
  __shared__ int cnt_s[SCAN_PAD];   // 7 KB
  __shared__ int off_s[SCAN_PAD];   // 7 KB (becomes cursors after chunkoff write)
  __shared__ int sb[256];
  const int bid = blockIdx.x;
  const int t = threadIdx.x;

  if (bid < NBLK) {
    const int ebase = bid * EPB;
    const int nch = min(EPB, N_EDGES - ebase);       // last chunk: 2560
    const int base4 = bid * (EPB / 4);
    const int end4 = base4 + (nch >> 2);             // nch divisible by 4

    for (int i = t; i < SCAN_PAD; i += 256) cnt_s[i] = 0;
    __syncthreads();

    // pass 1: histogram
#pragma unroll
    for (int k = 0; k < EPB / 1024; ++k) {
      int i4 = base4 + k * 256 + t;
      if (i4 < end4) {
        int4 r = ((const int4*)ei)[i4];
        atomicAdd(&cnt_s[r.x >> 6], 1);
        atomicAdd(&cnt_s[r.y >> 6], 1);
        atomicAdd(&cnt_s[r.z >> 6], 1);
        atomicAdd(&cnt_s[r.w >> 6], 1);
      }
    }
    __syncthreads();

    // blocked exclusive scan over SCAN_PAD (=256*7) entries
    int psum = 0;
#pragma unroll
    for (int i = 0; i < 7; ++i) psum += cnt_s[t * 7 + i];
    sb[t] = psum;
    __syncthreads();
    for (int off = 1; off < 256; off <<= 1) {
      int u = (t >= off) ? sb[t - off] : 0;
      __syncthreads();
      sb[t] += u;
      __syncthreads();
    }
    int run = sb[t] - psum;
#pragma unroll
    for (int i = 0; i < 7; ++i) {
      off_s[t * 7 + i] = run;
      run += cnt_s[t * 7 + i];
    }
    __syncthreads();

    // packed transposed chunkoff: chunkoff[b*NBLK + chunk] = beg | (len<<14)
    for (int b = t; b < NBUCKET; b += 256)
      chunkoff[b * NBLK + bid] = off_s[b] | (cnt_s[b] << 14);
    __syncthreads();

    // pass 2: LDS scatter into bucket-sorted order (off_s as cursors)
#pragma unroll
    for (int k = 0; k < EPB / 1024; ++k) {
      int i4 = base4 + k * 256 + t;
      if (i4 < end4) {
        int4 r = ((const int4*)ei)[i4];
        int4 c = ((const int4*)(ei + N_EDGES))[i4];
        int p0 = atomicAdd(&off_s[r.x >> 6], 1);
        ent_s[p0] = ((r.x & 63) << 17) | c.x;
        int p1 = atomicAdd(&off_s[r.y >> 6], 1);
        ent_s[p1] = ((r.y & 63) << 17) | c.y;
        int p2 = atomicAdd(&off_s[r.z >> 6], 1);
        ent_s[p2] = ((r.z & 63) << 17) | c.z;
        int p3 = atomicAdd(&off_s[r.w >> 6], 1);
        ent_s[p3] = ((r.w & 63) << 17) | c.w;
      }
    }
    __syncthreads();

    // dense coalesced write-out
    for (int i = t; i < nch; i += 256)
      ent_sorted[ebase + i] = (unsigned)ent_s[i];
  } else if (bid < NBLK + XCB) {
    // ---- xconv: thread t converts one full slice-row (16 consecutive floats
    // = cols [c, c+16) of one node, c = 16-col aligned). 64 B read, 32 B to
    // xb (row-major) and 32 B to xs (slice-major), all coalesced.
    const int f = (bid - NBLK) * 4096 + t * 16;      // flat float index
    const float4 v0 = ((const float4*)x)[(f >> 2) + 0];
    const float4 v1 = ((const float4*)x)[(f >> 2) + 1];
    const float4 v2 = ((const float4*)x)[(f >> 2) + 2];
    const float4 v3 = ((const float4*)x)[(f >> 2) + 3];
    uint4 lo, hi;
    lo.x = pack2(v0.x, v0.y); lo.y = pack2(v0.z, v0.w);
    lo.z = pack2(v1.x, v1.y); lo.w = pack2(v1.z, v1.w);
    hi.x = pack2(v2.x, v2.y); hi.y = pack2(v2.z, v2.w);
    hi.z = pack2(v3.x, v3.y); hi.w = pack2(v3.z, v3.w);
    *(uint4*)(xb + f) = lo;
    *(uint4*)(xb + f + 8) = hi;
    unsigned short* xd = xs + (size_t)((f >> 4) & 7) * SLICE_STRIDE
                            + (size_t)(f >> 7) * 16;
    *(uint4*)xd = lo;
    *(uint4*)(xd + 8) = hi;
  } else {
    // ---- wconv: 16 blocks cover 128x256 weights
    const int blk = bid - NBLK - XCB;
#pragma unroll
    for (int k = 0; k < 8; ++k) {
      int idx = blk * 2048 + k * 256 + t;
      int o = idx >> 8, kc = idx & 255;
      float v = (kc < 128) ? Wself[o * 128 + kc] : Wagg[o * 128 + (kc - 128)];
      wcat[o * 256 + kc] = f2bf(v);
    }
    if (blk == 0 && t < 128) bsum[t] = bself[t] + bagg[t];
  }
}

// ---------------------------------------------------------------------------
// row_sort: one block per bucket. Collect the bucket's entries from the 196
// chunk slices, counting-sort by row, write globally row-sorted col list +
// packed (beg|deg<<16) per node. Runs ONCE; the 8 slice blocks skip sorting.
// ---------------------------------------------------------------------------
__global__ __launch_bounds__(256) void row_sort(
    const unsigned* __restrict__ ent_sorted, const int* __restrict__ chunkoff,
    unsigned* __restrict__ col_sorted, unsigned* __restrict__ rowinfo) {
  __shared__ int ent_s[AGG_CAP];   // 5 KB
  __shared__ int col_s[AGG_CAP];   // 5 KB
  __shared__ int sb[256];
  __shared__ int cnt_s[RPB];
  __shared__ int off_s[RPB];
  __shared__ int cur_s[RPB];

  const int b = blockIdx.x;
  const int t = threadIdx.x;

  int beg = 0, len = 0;
  if (t < NBLK) {
    int pk = chunkoff[b * NBLK + t];
    beg = pk & 16383;
    len = pk >> 14;
  }
  sb[t] = len;
  __syncthreads();
  for (int off = 1; off < 256; off <<= 1) {
    int u = (t >= off) ? sb[t - off] : 0;
    __syncthreads();
    sb[t] += u;
    __syncthreads();
  }
  int n = sb[255]; if (n > AGG_CAP) n = AGG_CAP;
  int dst = sb[t] - len;
  if (t < NBLK) {
    const unsigned* src = ent_sorted + t * EPB + beg;
    for (int i = 0; i < len; ++i)
      if (dst + i < AGG_CAP) ent_s[dst + i] = (int)src[i];
  }
  __syncthreads();

  // row counting sort
  if (t < RPB) cnt_s[t] = 0;
  __syncthreads();
  for (int i = t; i < n; i += 256) atomicAdd(&cnt_s[ent_s[i] >> 17], 1);
  __syncthreads();
  if (t < RPB) off_s[t] = cnt_s[t];
  __syncthreads();
  for (int off = 1; off < RPB; off <<= 1) {
    int u = 0;
    if (t < RPB && t >= off) u = off_s[t - off];
    __syncthreads();
    if (t < RPB) off_s[t] += u;
    __syncthreads();
  }
  int excl = 0;
  if (t < RPB) excl = off_s[t] - cnt_s[t];
  __syncthreads();
  if (t < RPB) { off_s[t] = excl; cur_s[t] = excl; }
  __syncthreads();
  for (int i = t; i < n; i += 256) {
    int e = ent_s[i];
    int pos = atomicAdd(&cur_s[e >> 17], 1);
    col_s[pos] = e & 0x1FFFF;
  }
  __syncthreads();

  for (int i = t; i < n; i += 256)
    __builtin_nontemporal_store((unsigned)col_s[i],
                                col_sorted + (size_t)b * AGG_CAP + i);
  if (t < RPB)
    __builtin_nontemporal_store((unsigned)off_s[t] | ((unsigned)cnt_s[t] << 16),
                                rowinfo + b * RPB + t);
}

// ---------------------------------------------------------------------------
// agg_slice: grid = NBUCKET*8, block (b = bid>>3, g = bid&7). With round-robin
// dispatch, bid&7 == XCD id -> slice g's CONTIGUOUS 3.2 MB region of
// slice-major xs stays resident in XCD g's 4 MB L2; every 32 B gather is
// fully used and (after first touch) an L2 hit. Col lists streamed with NT
// loads so they never evict the hot slice. 32 groups x 8 lanes; lane owns
// 2 of the slice's 16 cols. Mean stored bf16 into out-row bytes
// [g*32, g*32+32) — the format gemm expects.
// ---------------------------------------------------------------------------
__global__ __launch_bounds__(256) void agg_slice(
    const unsigned short* __restrict__ xs, const unsigned* __restrict__ col_sorted,
    const unsigned* __restrict__ rowinfo, float* __restrict__ out) {
  __shared__ unsigned cols_s[AGG_CAP];  // 5 KB
  __shared__ unsigned ri_s[RPB];

  const int bid = blockIdx.x;
  const int g = bid & 7;                // XCD slice
  const int b = bid >> 3;               // bucket
  const int t = threadIdx.x;

  if (t < RPB) ri_s[t] = __builtin_nontemporal_load(rowinfo + b * RPB + t);
  __syncthreads();
  const int n = (int)(ri_s[RPB - 1] & 0xFFFFu) + (int)(ri_s[RPB - 1] >> 16);
  for (int i = t; i < n; i += 256)
    cols_s[i] = __builtin_nontemporal_load(col_sorted + (size_t)b * AGG_CAP + i);
  __syncthreads();

  const int grp = t >> 3, gl = t & 7;   // 32 groups x 8 lanes
  const unsigned short* xg = xs + g * SLICE_STRIDE + gl * 2;  // + col*16 ushorts

  for (int rr = grp; rr < RPB; rr += 32) {
    const unsigned ri = ri_s[rr];
    const int rbeg = (int)(ri & 0xFFFFu);
    const int deg = (int)(ri >> 16);
    float a0 = 0.f, a1 = 0.f;
    int j = 0;
    for (; j + 8 <= deg; j += 8) {
      unsigned p[8];
#pragma unroll
      for (int u = 0; u < 8; ++u) {
        unsigned col = cols_s[rbeg + j + u];
        p[u] = *(const unsigned*)(xg + (size_t)col * 16);
      }
#pragma unroll
      for (int u = 0; u < 8; ++u) { a0 += bflo(p[u]); a1 += bfhi(p[u]); }
    }
    if (j + 4 <= deg) {
      unsigned p[4];
#pragma unroll
      for (int u = 0; u < 4; ++u) {
        unsigned col = cols_s[rbeg + j + u];
        p[u] = *(const unsigned*)(xg + (size_t)col * 16);
      }
#pragma unroll
      for (int u = 0; u < 4; ++u) { a0 += bflo(p[u]); a1 += bfhi(p[u]); }
      j += 4;
    }
    for (; j < deg; ++j) {
      unsigned col = cols_s[rbeg + j];
      unsigned p = *(const unsigned*)(xg + (size_t)col * 16);
      a0 += bflo(p); a1 += bfhi(p);
    }
    const int node = (b << 6) + rr;
    if (node < N_NODES) {
      float inv = 1.0f / ((float)deg + MEAN_EPS);
      unsigned o = (unsigned)f2bf(a0 * inv) | ((unsigned)f2bf(a1 * inv) << 16);
      __builtin_nontemporal_store(o, (unsigned*)(out + (size_t)node * D) + g * 8 + gl);
    }
  }
}

// ---------------------------------------------------------------------------
// MFMA GEMM: C[100000x128] = [x_bf16 | mean_bf16] (K=256) @ Wcat^T + ReLU + LN
// B-only LDS (67.6 KB -> 2 blocks/CU), A streamed global->frags, per-wave
// in-register LN epilogue. (unchanged)
// ---------------------------------------------------------------------------
__global__ __launch_bounds__(512, 4) void gemm_mfma_ln(
    const unsigned short* __restrict__ xb, const float* out_mean,
    const unsigned short* __restrict__ wcat, const float* __restrict__ bsum,
    const float* __restrict__ gamma, const float* __restrict__ beta,
    float* out) {
  __shared__ unsigned short Bs[128 * 264];   // 67.6 KB
  __shared__ float bias_s[128];

  const int t = threadIdx.x;
  const int w = t >> 6, lane = t & 63;
  const int q = lane >> 4, s = lane & 15;
  const int base = blockIdx.x * 128;

  if (t < 128) bias_s[t] = bsum[t];

#pragma unroll
  for (int r = 0; r < 8; ++r) {
    int f = r * 512 + t;
    int row = f >> 5, c = f & 31;
    uint4 v = *(const uint4*)(wcat + row * 256 + c * 8);
    *(uint4*)(Bs + row * 264 + c * 8) = v;
  }

  const int arow = base + w * 16 + s;
  const int asafe = (arow < N_NODES) ? arow : 0;
  const unsigned short* xrow = xb + (size_t)asafe * 128;
  const unsigned short* mrow = (const unsigned short*)(out_mean + (size_t)asafe * 128);
  bf16x8 a[8];
#pragma unroll
  for (int kk = 0; kk < 4; ++kk)
    a[kk] = *(const bf16x8*)(xrow + kk * 32 + q * 8);
#pragma unroll
  for (int kk = 0; kk < 4; ++kk)
    a[4 + kk] = *(const bf16x8*)(mrow + kk * 32 + q * 8);

  __syncthreads();

  f32x4 acc[8];
#pragma unroll
  for (int j = 0; j < 8; ++j) acc[j] = (f32x4)(0.0f);

#pragma unroll
  for (int kk = 0; kk < 8; ++kk) {
    const int ko = kk * 32 + q * 8;
#pragma unroll
    for (int j = 0; j < 8; ++j) {
      bf16x8 bv = *(const bf16x8*)(Bs + (j * 16 + s) * 264 + ko);
      acc[j] = __builtin_amdgcn_mfma_f32_16x16x32_bf16(a[kk], bv, acc[j], 0, 0, 0);
    }
  }

#pragma unroll
  for (int j = 0; j < 8; ++j) {
    float bb = bias_s[j * 16 + s];
#pragma unroll
    for (int r = 0; r < 4; ++r)
      acc[j][r] = fmaxf(acc[j][r] + bb, 0.0f);
  }

  float g[8], be[8];
#pragma unroll
  for (int j = 0; j < 8; ++j) {
    g[j]  = gamma[j * 16 + s];
    be[j] = beta[j * 16 + s];
  }

#pragma unroll
  for (int r = 0; r < 4; ++r) {
    float s1 = 0.f, s2 = 0.f;
#pragma unroll
    for (int j = 0; j < 8; ++j) {
      float h = acc[j][r];
      s1 += h; s2 += h * h;
    }
#pragma unroll
    for (int m = 1; m < 16; m <<= 1) {
      s1 += __shfl_xor(s1, m, 64);
      s2 += __shfl_xor(s2, m, 64);
    }
    int node = base + w * 16 + q * 4 + r;
    if (node < N_NODES) {
      float mu = s1 * (1.0f / 128.0f);
      float var = s2 * (1.0f / 128.0f) - mu * mu;
      float rstd = rsqrtf(var + LN_EPS);
      float* orow = out + (size_t)node * 128;
#pragma unroll
      for (int j = 0; j < 8; ++j)
        orow[j * 16 + s] = (acc[j][r] - mu) * rstd * g[j] + be[j];
    }
  }
}

extern "C" void kernel_launch(void* const* d_in, const int* in_sizes, int n_in,
                              void* d_out, int out_size, void* d_ws, size_t ws_size,
                              hipStream_t stream) {
  const float* x     = (const float*)d_in[0];
  const int*   ei    = (const int*)d_in[1];
  const float* Wagg  = (const float*)d_in[2];
  const float* bagg  = (const float*)d_in[3];
  const float* Wself = (const float*)d_in[4];
  const float* bself = (const float*)d_in[5];
  const float* gamma = (const float*)d_in[6];
  const float* beta  = (const float*)d_in[7];
  float* out = (float*)d_out;

  // ws: xb | xs | wcat | bsum | ent_sorted | chunkoff | col_sorted | rowinfo (~67 MB)
  unsigned short* xb   = (unsigned short*)d_ws;                 // 25.6 MB row-major
  unsigned short* xs   = xb + (size_t)N_NODES * D;              // 25.6 MB slice-major
  unsigned short* wcat = xs + (size_t)N_NODES * D;              // 64 KB
  float* bsum      = (float*)(wcat + 128 * 256);                // 512 B
  unsigned* ent_sorted = (unsigned*)(bsum + 128);               // NBLK*EPB u32 (6.4 MB)
  int* chunkoff    = (int*)(ent_sorted + (size_t)NBLK * EPB);   // NBUCKET*NBLK (1.2 MB)
  unsigned* col_sorted = (unsigned*)(chunkoff + (size_t)NBUCKET * NBLK); // 8.0 MB
  unsigned* rowinfo    = col_sorted + (size_t)NBUCKET * AGG_CAP;         // 0.4 MB

  prep_sort<<<NBLK + XCB + 16, 256, 0, stream>>>(
      x, ei, Wself, Wagg, bself, bagg, xb, xs, wcat, bsum, ent_sorted, chunkoff);

  row_sort<<<NBUCKET, 256, 0, stream>>>(ent_sorted, chunkoff, col_sorted, rowinfo);

  agg_slice<<<NBUCKET * NSLICE, 256, 0, stream>>>(xs, col_sorted, rowinfo, out);

  gemm_mfma_ln<<<(N_NODES + 127) / 128, 512, 0, stream>>>(
      xb, out, wcat, bsum, gamma, beta, out);
}